// Round 10
// baseline (207.548 us; speedup 1.0000x reference)
//
#include <hip/hip_runtime.h>

#define SQ 2048
#define DH 64
#define NH 12
#define NBH 24

typedef __attribute__((ext_vector_type(8))) short short8;
typedef __attribute__((ext_vector_type(16))) float f32x16;

union U8 { uint4 u; short8 s; };

__device__ __forceinline__ unsigned short f2bf(float x) {
  union { float f; unsigned u; } v; v.f = x;
  return (unsigned short)((v.u + 0x7FFFu + ((v.u >> 16) & 1u)) >> 16);
}

// pack two fp32 -> bf16x2 (a=low element, b=high); +0x8000 round, v_perm merge
__device__ __forceinline__ unsigned pk2(float a, float b) {
  unsigned ua = __builtin_bit_cast(unsigned, a) + 0x8000u;
  unsigned ub = __builtin_bit_cast(unsigned, b) + 0x8000u;
  return __builtin_amdgcn_perm(ub, ua, 0x07060302);
}

__device__ __forceinline__ float bflo(unsigned w) {
  return __builtin_bit_cast(float, w << 16);
}
__device__ __forceinline__ float bfhi(unsigned w) {
  return __builtin_bit_cast(float, w & 0xFFFF0000u);
}

// swap bits 2<->3 of a 5-bit index (sigma for the 32x32 C-layout -> B-frag trick)
__device__ __forceinline__ int sw23(int x) {
  return (x & 19) | ((x & 4) << 1) | ((x & 8) >> 1);
}

// Fused prep: [0,3072) Q*scale+K -> bf16 | [3072,3840) V transpose | [3840,4864) mask ballot-pack
__global__ __launch_bounds__(256) void prep_all(
    const float* __restrict__ Q, const float* __restrict__ K,
    const float* __restrict__ V, const int* __restrict__ M,
    unsigned short* __restrict__ Qb, unsigned short* __restrict__ Kb,
    unsigned short* __restrict__ Vt, unsigned* __restrict__ mbits) {
  const int bid = blockIdx.x, tid = threadIdx.x;
  if (bid < 3072) {
    int i = bid * 256 + tid;
    float4 q = ((const float4*)Q)[i];
    float4 k = ((const float4*)K)[i];
    const float sc = 0.125f * 1.44269504f;   // fold log2(e): scores feed exp2 directly
    ushort4 qo, ko;
    qo.x = f2bf(q.x * sc); qo.y = f2bf(q.y * sc);
    qo.z = f2bf(q.z * sc); qo.w = f2bf(q.w * sc);
    ko.x = f2bf(k.x); ko.y = f2bf(k.y); ko.z = f2bf(k.z); ko.w = f2bf(k.w);
    ((ushort4*)Qb)[i] = qo;
    ((ushort4*)Kb)[i] = ko;
  } else if (bid < 3840) {
    __shared__ float T[64 * 65];
    int bx = bid - 3072;
    int bh = bx >> 5, st = bx & 31;
    int s0 = st * 64;
    int c4 = (tid & 15) * 4, r0 = tid >> 4;
#pragma unroll
    for (int it = 0; it < 4; ++it) {
      int r = r0 + 16 * it;
      float4 v = *(const float4*)(V + ((size_t)(bh * SQ + s0 + r)) * DH + c4);
      T[r * 65 + c4 + 0] = v.x; T[r * 65 + c4 + 1] = v.y;
      T[r * 65 + c4 + 2] = v.z; T[r * 65 + c4 + 3] = v.w;
    }
    __syncthreads();
#pragma unroll
    for (int it = 0; it < 2; ++it) {
      int cc = tid + 256 * it;
      int d = cc >> 3, c8 = (cc & 7) * 8;
      short8 o;
#pragma unroll
      for (int j = 0; j < 8; ++j) o[j] = (short)f2bf(T[(c8 + j) * 65 + d]);
      *(short8*)(Vt + ((size_t)(bh * 64 + d)) * SQ + s0 + c8) = o;
    }
  } else {
    // ballot mask pack, coalesced: wave handles one (b,q) row; 32 chunks of 64 k
    int w = tid >> 6, lane = tid & 63;
    int row = (bid - 3840) * 4 + w;                 // [0, 4096)
    const int* mrow = M + (size_t)row * SQ;
    unsigned long long out = 0;
#pragma unroll
    for (int j = 0; j < 32; ++j) {
      int mv = mrow[j * 64 + lane];
      unsigned long long bits = __ballot(mv != 0);  // bit k of chunk j
      if (lane == j) out = bits;
    }
    if (lane < 32)
      ((unsigned long long*)mbits)[(size_t)row * 32 + lane] = out;
  }
}

// Flash attention, S^T form, 32x32x16 MFMA shape. Grid = 24 bh x 16 qt x 2 ks
// = 768 blocks x 256 thr. Block = 128 q (4 waves x 32 q), 16 iters of 64 k.
//
// ROUND-10 CHANGE: NO LDS, NO BARRIERS. The FIFO staging was pure cross-wave
// redundancy elimination: consuming lane l read FIFO[c][l], which holds the
// bytes lane l of the staging wave fetched from addr(c, n, h) -- an address
// the consumer can compute itself. K+Vt per bh (512 KB, x3 bh per XCD via the
// bh%8 affinity = 1.5 MB) is L2-resident, so each wave now loads its MFMA
// fragments DIRECTLY from global (same formulas, sigma baked into the K row).
// This deletes: global_load_lds issue, 16 ds_read_b128/wave/iter of LDS-pipe
// contention, and the per-iter vmcnt(0)+s_barrier lockstep. Waves free-run;
// TLP (12 waves/CU) hides L2 latency (~200 cyc/iter group, issued 8-deep).
// L2 re-read traffic x4 (786 MB ~ 23 us at L2 ceiling: not binding). Load
// placement keeps the rotating live set <= ~48 regs: K(u0,u1) issued up
// front, V issued between QKT(u0) and exp(u0) so PV-use is ~500 cyc later.
__global__ __launch_bounds__(256, 3) void attn_kernel(
    const unsigned short* __restrict__ Qb, const unsigned short* __restrict__ Kb,
    const unsigned short* __restrict__ Vt, const unsigned* __restrict__ mbits,
    unsigned short* __restrict__ Ob, float* __restrict__ Lp) {
  const int bx = blockIdx.x;
  const int bh = bx % NBH;            // 24 = 0 mod 8: all blocks of a bh share an XCD
  const int rest = bx / NBH;
  const int qt = rest & 15, ks = rest >> 4;
  const int b = bh / NH;
  const int tid = threadIdx.x;
  const int lane = tid & 63, w = tid >> 6;
  const int n = lane & 31, h = lane >> 5;
  const int qrow = qt * 128 + w * 32 + n;
  const int k0 = ks * (SQ / 2);

  // Q B-frags for 32x32x16: B[n=q=lane&31][kk=8h+j], 4 d-slices (16 VGPRs)
  short8 qf[4];
#pragma unroll
  for (int s = 0; s < 4; ++s)
    qf[s] = *(const short8*)(Qb + ((size_t)(bh * SQ + qrow)) * DH + 16 * s + 8 * h);

  // direct per-lane fragment bases (formerly the staging addresses):
  // K A-frag (u,s): row k0 + 64nt + 32u + sw23(n), col 16s + 8h
  const unsigned short* kp[2];
#pragma unroll
  for (int u = 0; u < 2; ++u)
    kp[u] = Kb + ((size_t)bh * SQ + k0 + 32 * u + sw23(n)) * DH + 8 * h;
  // V^T A-frag (dt,t): row 32*dt + n (of Vt's [bh*DH] rows), col k0 + 64nt + 16t + 8h
  const unsigned short* vp[2];
#pragma unroll
  for (int dt = 0; dt < 2; ++dt)
    vp[dt] = Vt + ((size_t)bh * DH + 32 * dt + n) * SQ + k0 + 8 * h;

  const unsigned long long* mp =
      (const unsigned long long*)mbits + ((size_t)b * SQ + qrow) * 32 + (k0 >> 6);

  short8 ones;
#pragma unroll
  for (int j = 0; j < 8; ++j) ones[j] = (short)0x3F80;  // bf16 1.0

  f32x16 acc0 = {0,0,0,0,0,0,0,0,0,0,0,0,0,0,0,0};
  f32x16 acc1 = {0,0,0,0,0,0,0,0,0,0,0,0,0,0,0,0};
  f32x16 sumac = {0,0,0,0,0,0,0,0,0,0,0,0,0,0,0,0};

  for (int nt = 0; nt < 16; ++nt) {
    unsigned long long mg = *mp; ++mp;

    // ---- issue all 8 K fragment loads (L2-resident; 8-deep in flight) ----
    U8 kf0[4], kf1[4];
#pragma unroll
    for (int s = 0; s < 4; ++s) kf0[s].u = *(const uint4*)(kp[0] + 16 * s);
#pragma unroll
    for (int s = 0; s < 4; ++s) kf1[s].u = *(const uint4*)(kp[1] + 16 * s);

    // ---- QK^T u=0 (4 chained 32x32x16) ----
    f32x16 st0 = {0,0,0,0,0,0,0,0,0,0,0,0,0,0,0,0};
#pragma unroll
    for (int s = 0; s < 4; ++s)
      st0 = __builtin_amdgcn_mfma_f32_32x32x16_bf16(kf0[s].s, qf[s], st0, 0, 0, 0);

    // ---- issue V loads now: ~500 cyc (exp u0 + QKT u1 + exp u1) to land ----
    U8 vf0[4], vf1[4];
#pragma unroll
    for (int t = 0; t < 4; ++t) vf0[t].u = *(const uint4*)(vp[0] + 16 * t);
#pragma unroll
    for (int t = 0; t < 4; ++t) vf1[t].u = *(const uint4*)(vp[1] + 16 * t);

    // ---- u=0: mask+exp2+pack (reg j: k_local = (j&7) + 8h + 16*(j>>3)) ----
    short8 pb[2][2];
    {
      unsigned blo = (unsigned)(mg >> (8 * (0 + h))) & 0xFFu;
      unsigned bhi = (unsigned)(mg >> (8 * (2 + h))) & 0xFFu;
      float p[16];
#pragma unroll
      for (int j = 0; j < 16; ++j) {
        float e = __builtin_amdgcn_exp2f(st0[j]);
        unsigned byt = (j < 8) ? blo : bhi;
        p[j] = ((byt >> (j & 7)) & 1u) ? e : 0.f;
      }
      U8 x0, x1;
      x0.u = (uint4){pk2(p[0], p[1]), pk2(p[2], p[3]), pk2(p[4], p[5]), pk2(p[6], p[7])};
      x1.u = (uint4){pk2(p[8], p[9]), pk2(p[10], p[11]), pk2(p[12], p[13]), pk2(p[14], p[15])};
      pb[0][0] = x0.s; pb[0][1] = x1.s;
    }

    // ---- QK^T u=1 then mask+exp2+pack ----
    f32x16 st1 = {0,0,0,0,0,0,0,0,0,0,0,0,0,0,0,0};
#pragma unroll
    for (int s = 0; s < 4; ++s)
      st1 = __builtin_amdgcn_mfma_f32_32x32x16_bf16(kf1[s].s, qf[s], st1, 0, 0, 0);
    {
      unsigned blo = (unsigned)(mg >> (8 * (4 + h))) & 0xFFu;
      unsigned bhi = (unsigned)(mg >> (8 * (6 + h))) & 0xFFu;
      float p[16];
#pragma unroll
      for (int j = 0; j < 16; ++j) {
        float e = __builtin_amdgcn_exp2f(st1[j]);
        unsigned byt = (j < 8) ? blo : bhi;
        p[j] = ((byt >> (j & 7)) & 1u) ? e : 0.f;
      }
      U8 x0, x1;
      x0.u = (uint4){pk2(p[0], p[1]), pk2(p[2], p[3]), pk2(p[4], p[5]), pk2(p[6], p[7])};
      x1.u = (uint4){pk2(p[8], p[9]), pk2(p[10], p[11]), pk2(p[12], p[13]), pk2(p[14], p[15])};
      pb[1][0] = x0.s; pb[1][1] = x1.s;
    }

    // ---- sum (ones-A) + O^T += V^T P^T, 4 k-steps of 16 ----
#pragma unroll
    for (int t = 0; t < 4; ++t) {
      short8 pf = pb[t >> 1][t & 1];
      sumac = __builtin_amdgcn_mfma_f32_32x32x16_bf16(ones, pf, sumac, 0, 0, 0);
      acc0 = __builtin_amdgcn_mfma_f32_32x32x16_bf16(vf0[t].s, pf, acc0, 0, 0, 0);
      acc1 = __builtin_amdgcn_mfma_f32_32x32x16_bf16(vf1[t].s, pf, acc1, 0, 0, 0);
    }

    kp[0] += 64 * DH; kp[1] += 64 * DH;
    vp[0] += 64;      vp[1] += 64;
  }

  // ---- epilogue: bf16 partial rows into Out (row-interleaved) + l ----
  // ushort offset = 128*row + 64*ks + d, d = 32*dt + 8*a + 4*h (uint2 = 4 elems)
  unsigned short* rb = Ob + 128 * (size_t)(bh * SQ + qrow) + 64 * ks;
#pragma unroll
  for (int dt = 0; dt < 2; ++dt) {
    f32x16 A = dt ? acc1 : acc0;
#pragma unroll
    for (int a = 0; a < 4; ++a) {
      uint2 o = {pk2(A[4 * a], A[4 * a + 1]), pk2(A[4 * a + 2], A[4 * a + 3])};
      *(uint2*)(rb + 32 * dt + 8 * a + 4 * h) = o;
    }
  }
  if (lane < 32) Lp[(size_t)ks * NBH * SQ + bh * SQ + qrow] = sumac[0];
}

// In-place combine: thread i handles out floats [4i,4i+4) = row r=i>>4,
// d0=(i&15)*4. Reads row r's two bf16 partial rows from Out bytes
// [256r + 2*d0] and [256r + 128 + 2*d0], writes normalized float4 at byte
// 16i (within [256r,256r+256)). Row r's 256 bytes are touched ONLY by lanes
// 16r..16r+15 of one wave; the store data-depends on the loads, so the
// wave's loads complete before its store issues — no hazard.
__global__ __launch_bounds__(256) void combine(float* __restrict__ Out,
                                               const float* __restrict__ Lp) {
  int i = blockIdx.x * 256 + threadIdx.x;    // float4 index
  int r = i >> 4;                            // global row (bh*SQ + q)
  int d0 = (i & 15) * 4;
  const unsigned short* ob = (const unsigned short*)Out;
  uint2 p0 = *(const uint2*)(ob + 128 * (size_t)r + d0);
  uint2 p1 = *(const uint2*)(ob + 128 * (size_t)r + 64 + d0);
  float inv = __builtin_amdgcn_rcpf(Lp[r] + Lp[NBH * SQ + r]);
  float4 o = {(bflo(p0.x) + bflo(p1.x)) * inv, (bfhi(p0.x) + bfhi(p1.x)) * inv,
              (bflo(p0.y) + bflo(p1.y)) * inv, (bfhi(p0.y) + bfhi(p1.y)) * inv};
  ((float4*)Out)[i] = o;
}

extern "C" void kernel_launch(void* const* d_in, const int* in_sizes, int n_in,
                              void* d_out, int out_size, void* d_ws, size_t ws_size,
                              hipStream_t stream) {
  const float* Q = (const float*)d_in[0];
  const float* K = (const float*)d_in[1];
  const float* V = (const float*)d_in[2];
  const int*   M = (const int*)d_in[3];
  float* Out = (float*)d_out;

  size_t NB = (size_t)NBH * SQ * DH;            // 3,145,728
  unsigned short* Qb = (unsigned short*)d_ws;
  unsigned short* Kb = Qb + NB;
  unsigned short* Vt = Kb + NB;
  unsigned* mbits = (unsigned*)(Vt + NB);       // 1 MB
  float* Lp = (float*)(mbits + (size_t)2 * SQ * 64);  // 2 * 49152 floats
  // total ws: 18.87 + 1.05 + 0.39 = 20.3 MB

  prep_all<<<4864, 256, 0, stream>>>(Q, K, V, M, Qb, Kb, Vt, mbits);
  attn_kernel<<<NBH * 16 * 2, 256, 0, stream>>>(Qb, Kb, Vt, mbits,
                                                (unsigned short*)Out, Lp);
  combine<<<(int)(NB / 4 / 256), 256, 0, stream>>>(Out, Lp);
}

// Round 11
// 154.432 us; speedup vs baseline: 1.3439x; 1.3439x over previous
//
#include <hip/hip_runtime.h>

#define SQ 2048
#define DH 64
#define NH 12
#define NBH 24

typedef __attribute__((ext_vector_type(8))) short short8;
typedef __attribute__((ext_vector_type(16))) float f32x16;

union U8 { uint4 u; short8 s; };

__device__ __forceinline__ unsigned short f2bf(float x) {
  union { float f; unsigned u; } v; v.f = x;
  return (unsigned short)((v.u + 0x7FFFu + ((v.u >> 16) & 1u)) >> 16);
}

// pack two fp32 -> bf16x2 (a=low element, b=high); +0x8000 round, v_perm merge
__device__ __forceinline__ unsigned pk2(float a, float b) {
  unsigned ua = __builtin_bit_cast(unsigned, a) + 0x8000u;
  unsigned ub = __builtin_bit_cast(unsigned, b) + 0x8000u;
  return __builtin_amdgcn_perm(ub, ua, 0x07060302);
}

__device__ __forceinline__ float bflo(unsigned w) {
  return __builtin_bit_cast(float, w << 16);
}
__device__ __forceinline__ float bfhi(unsigned w) {
  return __builtin_bit_cast(float, w & 0xFFFF0000u);
}

// async global->LDS, 16 B/lane: data lands at lds_base + lane*16 (wave-uniform base)
__device__ __forceinline__ void gload_lds16(const void* g, void* l) {
  __builtin_amdgcn_global_load_lds(
      (const __attribute__((address_space(1))) unsigned*)g,
      (__attribute__((address_space(3))) unsigned*)l, 16, 0, 0);
}

// swap bits 2<->3 of a 5-bit index (sigma for the 32x32 C-layout -> B-frag trick)
__device__ __forceinline__ int sw23(int x) {
  return (x & 19) | ((x & 4) << 1) | ((x & 8) >> 1);
}

// Fused prep: [0,3072) Q*scale+K -> bf16 | [3072,3840) V transpose | [3840,4864) mask ballot-pack
__global__ __launch_bounds__(256) void prep_all(
    const float* __restrict__ Q, const float* __restrict__ K,
    const float* __restrict__ V, const int* __restrict__ M,
    unsigned short* __restrict__ Qb, unsigned short* __restrict__ Kb,
    unsigned short* __restrict__ Vt, unsigned* __restrict__ mbits) {
  const int bid = blockIdx.x, tid = threadIdx.x;
  if (bid < 3072) {
    int i = bid * 256 + tid;
    float4 q = ((const float4*)Q)[i];
    float4 k = ((const float4*)K)[i];
    const float sc = 0.125f * 1.44269504f;   // fold log2(e): scores feed exp2 directly
    ushort4 qo, ko;
    qo.x = f2bf(q.x * sc); qo.y = f2bf(q.y * sc);
    qo.z = f2bf(q.z * sc); qo.w = f2bf(q.w * sc);
    ko.x = f2bf(k.x); ko.y = f2bf(k.y); ko.z = f2bf(k.z); ko.w = f2bf(k.w);
    ((ushort4*)Qb)[i] = qo;
    ((ushort4*)Kb)[i] = ko;
  } else if (bid < 3840) {
    __shared__ float T[64 * 65];
    int bx = bid - 3072;
    int bh = bx >> 5, st = bx & 31;
    int s0 = st * 64;
    int c4 = (tid & 15) * 4, r0 = tid >> 4;
#pragma unroll
    for (int it = 0; it < 4; ++it) {
      int r = r0 + 16 * it;
      float4 v = *(const float4*)(V + ((size_t)(bh * SQ + s0 + r)) * DH + c4);
      T[r * 65 + c4 + 0] = v.x; T[r * 65 + c4 + 1] = v.y;
      T[r * 65 + c4 + 2] = v.z; T[r * 65 + c4 + 3] = v.w;
    }
    __syncthreads();
#pragma unroll
    for (int it = 0; it < 2; ++it) {
      int cc = tid + 256 * it;
      int d = cc >> 3, c8 = (cc & 7) * 8;
      short8 o;
#pragma unroll
      for (int j = 0; j < 8; ++j) o[j] = (short)f2bf(T[(c8 + j) * 65 + d]);
      *(short8*)(Vt + ((size_t)(bh * 64 + d)) * SQ + s0 + c8) = o;
    }
  } else {
    // ballot mask pack, coalesced: wave handles one (b,q) row; 32 chunks of 64 k
    int w = tid >> 6, lane = tid & 63;
    int row = (bid - 3840) * 4 + w;                 // [0, 4096)
    const int* mrow = M + (size_t)row * SQ;
    unsigned long long out = 0;
#pragma unroll
    for (int j = 0; j < 32; ++j) {
      int mv = mrow[j * 64 + lane];
      unsigned long long bits = __ballot(mv != 0);  // bit k of chunk j
      if (lane == j) out = bits;
    }
    if (lane < 32)
      ((unsigned long long*)mbits)[(size_t)row * 32 + lane] = out;
  }
}

// Flash attention, S^T form, 32x32x16 MFMA shape. Grid = 24 bh x 16 qt x 2 ks
// = 768 blocks x 256 thr. Block = 128 q (4 waves x 32 q), 16 iters of 64 k.
// LDS FIFO double-buffered via async global_load_lds; 16 chunks/tile in exact
// consumption order. Serial per-iteration schedule (QKT(u)->exp(u) x2 ->
// PV(0..3)): measured optimal for the 64+48-reg budget (R8 reorder spilled,
// 54->70 us). LDS staging is load-bearing (R10 direct-load variant: 2x slower
// from uncoalesced L2 traffic). Counted-vmcnt pipelining null (R3: the
// vmcnt(0)-before-barrier drain is free at ~2760 cyc/iter). Epilogue: bf16
// partial rows interleaved inside Out (row r = bytes [256r,256r+256) as
// [P0 row|P1 row]), full-line writes, no partial-line RMW.
__global__ __launch_bounds__(256, 3) void attn_kernel(
    const unsigned short* __restrict__ Qb, const unsigned short* __restrict__ Kb,
    const unsigned short* __restrict__ Vt, const unsigned* __restrict__ mbits,
    unsigned short* __restrict__ Ob, float* __restrict__ Lp) {
  __shared__ uint4 FIFO[2][16][64];   // 32 KB: [buf][chunk][lane]

  const int bx = blockIdx.x;
  const int bh = bx % NBH;            // 24 = 0 mod 8: all blocks of a bh share an XCD
  const int rest = bx / NBH;
  const int qt = rest & 15, ks = rest >> 4;
  const int b = bh / NH;
  const int tid = threadIdx.x;
  const int lane = tid & 63, w = tid >> 6;
  const int n = lane & 31, h = lane >> 5;
  const int qrow = qt * 128 + w * 32 + n;
  const int k0 = ks * (SQ / 2);

  // Q B-frags for 32x32x16: B[n=q=lane&31][kk=8h+j], 4 d-slices (16 VGPRs)
  short8 qf[4];
#pragma unroll
  for (int s = 0; s < 4; ++s)
    qf[s] = *(const short8*)(Qb + ((size_t)(bh * SQ + qrow)) * DH + 16 * s + 8 * h);

  // staging: wave w owns chunks [4w,4w+4). c<8: K (u=c>>2, slice=c&3), sigma
  // baked into row; c>=8: V^T (dtile=(c-8)>>2, step=(c-8)&3).
  const unsigned short* gp[4];
  if (w < 2) {
#pragma unroll
    for (int j = 0; j < 4; ++j) {
      int c = 4 * w + j;
      int row = k0 + 32 * (c >> 2) + sw23(n);
      gp[j] = Kb + ((size_t)bh * SQ + row) * DH + 16 * (c & 3) + 8 * h;
    }
  } else {
#pragma unroll
    for (int j = 0; j < 4; ++j) {
      int cc = 4 * (w - 2) + j;
      gp[j] = Vt + ((size_t)bh * DH + 32 * (cc >> 2) + n) * SQ + k0 + 16 * (cc & 3) + 8 * h;
    }
  }
  const int gstride = (w < 2) ? 64 * DH : 64;
  const int chunk0 = w * 4;

  const unsigned long long* mp =
      (const unsigned long long*)mbits + ((size_t)b * SQ + qrow) * 32 + (k0 >> 6);

  short8 ones;
#pragma unroll
  for (int j = 0; j < 8; ++j) ones[j] = (short)0x3F80;  // bf16 1.0

  f32x16 acc0 = {0,0,0,0,0,0,0,0,0,0,0,0,0,0,0,0};
  f32x16 acc1 = {0,0,0,0,0,0,0,0,0,0,0,0,0,0,0,0};
  f32x16 sumac = {0,0,0,0,0,0,0,0,0,0,0,0,0,0,0,0};

  // prologue: async-stage tile 0 into buffer 0
#pragma unroll
  for (int j = 0; j < 4; ++j) {
    gload_lds16(gp[j], &FIFO[0][chunk0 + j][0]);
    gp[j] += gstride;
  }
  __syncthreads();

  for (int nt = 0; nt < 16; ++nt) {
    const int cur = nt & 1;
    if (nt < 15) {
#pragma unroll
      for (int j = 0; j < 4; ++j) {
        gload_lds16(gp[j], &FIFO[1 - cur][chunk0 + j][0]);
        gp[j] += gstride;
      }
    }
    unsigned long long mg = *mp; ++mp;

    // ---- per k-half u: S^T (4 chained 32x32x16) then mask+exp2+pack ----
    short8 pb[2][2];
#pragma unroll
    for (int u = 0; u < 2; ++u) {
      f32x16 st = {0,0,0,0,0,0,0,0,0,0,0,0,0,0,0,0};
#pragma unroll
      for (int s = 0; s < 4; ++s) {
        U8 kf; kf.u = FIFO[cur][4 * u + s][lane];
        st = __builtin_amdgcn_mfma_f32_32x32x16_bf16(kf.s, qf[s], st, 0, 0, 0);
      }
      // reg j holds k_local = (j&7) + 8h + 16*(j>>3) + 32u
      unsigned blo = (unsigned)(mg >> (8 * (4 * u + h))) & 0xFFu;
      unsigned bhi = (unsigned)(mg >> (8 * (4 * u + 2 + h))) & 0xFFu;
      float p[16];
#pragma unroll
      for (int j = 0; j < 16; ++j) {
        float e = __builtin_amdgcn_exp2f(st[j]);
        unsigned byt = (j < 8) ? blo : bhi;
        p[j] = ((byt >> (j & 7)) & 1u) ? e : 0.f;
      }
      U8 x0, x1;
      x0.u = (uint4){pk2(p[0], p[1]), pk2(p[2], p[3]), pk2(p[4], p[5]), pk2(p[6], p[7])};
      x1.u = (uint4){pk2(p[8], p[9]), pk2(p[10], p[11]), pk2(p[12], p[13]), pk2(p[14], p[15])};
      pb[u][0] = x0.s;
      pb[u][1] = x1.s;
    }

    // ---- sum (ones-A) + O^T += V^T P^T, 4 k-steps of 16 ----
#pragma unroll
    for (int t = 0; t < 4; ++t) {
      short8 pf = pb[t >> 1][t & 1];
      sumac = __builtin_amdgcn_mfma_f32_32x32x16_bf16(ones, pf, sumac, 0, 0, 0);
      U8 v0; v0.u = FIFO[cur][8 + t][lane];
      acc0 = __builtin_amdgcn_mfma_f32_32x32x16_bf16(v0.s, pf, acc0, 0, 0, 0);
      U8 v1; v1.u = FIFO[cur][12 + t][lane];
      acc1 = __builtin_amdgcn_mfma_f32_32x32x16_bf16(v1.s, pf, acc1, 0, 0, 0);
    }

    __syncthreads();   // done with buf cur; prefetch into 1-cur drained here
  }

  // ---- epilogue: bf16 partial rows into Out (row-interleaved) + l ----
  // ushort offset = 128*row + 64*ks + d, d = 32*dt + 8*a + 4*h (uint2 = 4 elems)
  unsigned short* rb = Ob + 128 * (size_t)(bh * SQ + qrow) + 64 * ks;
#pragma unroll
  for (int dt = 0; dt < 2; ++dt) {
    f32x16 A = dt ? acc1 : acc0;
#pragma unroll
    for (int a = 0; a < 4; ++a) {
      uint2 o = {pk2(A[4 * a], A[4 * a + 1]), pk2(A[4 * a + 2], A[4 * a + 3])};
      *(uint2*)(rb + 32 * dt + 8 * a + 4 * h) = o;
    }
  }
  if (lane < 32) Lp[(size_t)ks * NBH * SQ + bh * SQ + qrow] = sumac[0];
}

// In-place combine: thread i handles out floats [4i,4i+4) = row r=i>>4,
// d0=(i&15)*4. Reads row r's two bf16 partial rows from Out bytes
// [256r + 2*d0] and [256r + 128 + 2*d0], writes normalized float4 at byte
// 16i (within [256r,256r+256)). Row r's 256 bytes are touched ONLY by lanes
// 16r..16r+15 of one wave; the store data-depends on the loads, so the
// wave's loads complete before its store issues — no hazard.
__global__ __launch_bounds__(256) void combine(float* __restrict__ Out,
                                               const float* __restrict__ Lp) {
  int i = blockIdx.x * 256 + threadIdx.x;    // float4 index
  int r = i >> 4;                            // global row (bh*SQ + q)
  int d0 = (i & 15) * 4;
  const unsigned short* ob = (const unsigned short*)Out;
  uint2 p0 = *(const uint2*)(ob + 128 * (size_t)r + d0);
  uint2 p1 = *(const uint2*)(ob + 128 * (size_t)r + 64 + d0);
  float inv = __builtin_amdgcn_rcpf(Lp[r] + Lp[NBH * SQ + r]);
  float4 o = {(bflo(p0.x) + bflo(p1.x)) * inv, (bfhi(p0.x) + bfhi(p1.x)) * inv,
              (bflo(p0.y) + bflo(p1.y)) * inv, (bfhi(p0.y) + bfhi(p1.y)) * inv};
  ((float4*)Out)[i] = o;
}

extern "C" void kernel_launch(void* const* d_in, const int* in_sizes, int n_in,
                              void* d_out, int out_size, void* d_ws, size_t ws_size,
                              hipStream_t stream) {
  const float* Q = (const float*)d_in[0];
  const float* K = (const float*)d_in[1];
  const float* V = (const float*)d_in[2];
  const int*   M = (const int*)d_in[3];
  float* Out = (float*)d_out;

  size_t NB = (size_t)NBH * SQ * DH;            // 3,145,728
  unsigned short* Qb = (unsigned short*)d_ws;
  unsigned short* Kb = Qb + NB;
  unsigned short* Vt = Kb + NB;
  unsigned* mbits = (unsigned*)(Vt + NB);       // 1 MB
  float* Lp = (float*)(mbits + (size_t)2 * SQ * 64);  // 2 * 49152 floats
  // total ws: 18.87 + 1.05 + 0.39 = 20.3 MB

  prep_all<<<4864, 256, 0, stream>>>(Q, K, V, M, Qb, Kb, Vt, mbits);
  attn_kernel<<<NBH * 16 * 2, 256, 0, stream>>>(Qb, Kb, Vt, mbits,
                                                (unsigned short*)Out, Lp);
  combine<<<(int)(NB / 4 / 256), 256, 0, stream>>>(Out, Lp);
}